// Round 2
// baseline (691.647 us; speedup 1.0000x reference)
//
#include <hip/hip_runtime.h>

// ---------------- problem constants ----------------
#define NNODES 100000
#define NEDGES 1600000
#define KDIM 256          // IN
#define CDIM 256          // H*F
#define NHEAD 4
#define FDIM 64
#define NEG 0.05f

typedef short bf16x8 __attribute__((ext_vector_type(8)));   // 8 bf16 in 4 VGPRs
typedef float f32x4  __attribute__((ext_vector_type(4)));
typedef __attribute__((address_space(3))) void*       lds_vp;
typedef __attribute__((address_space(1))) const void* glb_cvp;

__device__ __forceinline__ unsigned short f2b(float x) {   // fp32 -> bf16 RNE
    unsigned int u = __float_as_uint(x);
    return (unsigned short)((u + 0x7FFFu + ((u >> 16) & 1u)) >> 16);
}
__device__ __forceinline__ float b2f(unsigned short b) {
    return __uint_as_float(((unsigned int)b) << 16);
}
__device__ __forceinline__ float lrelu(float x) { return x > 0.f ? x : NEG * x; }

// monotone float<->uint mapping for atomicMax on signed floats
__device__ __forceinline__ unsigned int fmap(float f) {
    unsigned int u = __float_as_uint(f);
    return u ^ ((u >> 31) ? 0xFFFFFFFFu : 0x80000000u);
}
__device__ __forceinline__ float funmap(unsigned int u) {
    return __uint_as_float(u ^ ((u & 0x80000000u) ? 0x80000000u : 0xFFFFFFFFu));
}

// ---------------- fp32 -> bf16 converts ----------------
__global__ __launch_bounds__(256) void cvt_feat(const float* __restrict__ in,
                                                unsigned short* __restrict__ out)
{
    int i = (blockIdx.x * 256 + threadIdx.x) * 4;
    float4 v = *(const float4*)(in + i);
    ushort4 o;
    o.x = f2b(v.x); o.y = f2b(v.y); o.z = f2b(v.z); o.w = f2b(v.w);
    *(ushort4*)(out + i) = o;
}

__global__ __launch_bounds__(256) void cvt_w(const float* __restrict__ Wfc,
                                             const float* __restrict__ Wres,
                                             unsigned short* __restrict__ out)
{
    int i = (blockIdx.x * 256 + threadIdx.x) * 4;   // 131072 total
    float4 v = (i < 65536) ? *(const float4*)(Wfc + i)
                           : *(const float4*)(Wres + (i - 65536));
    ushort4 o;
    o.x = f2b(v.x); o.y = f2b(v.y); o.z = f2b(v.z); o.w = f2b(v.w);
    *(ushort4*)(out + i) = o;
}

// ---------------- bf16 MFMA dual GEMM + fused el/er epilogue ----------------
__global__ __launch_bounds__(256) void gemm_mfma(
    const unsigned short* __restrict__ featb,   // [N][256] bf16
    const unsigned short* __restrict__ Wb,      // [512][256] bf16
    const float* __restrict__ bias,
    const float* __restrict__ attn_l, const float* __restrict__ attn_r,
    unsigned short* __restrict__ fsb,           // [N][256] bf16
    float* __restrict__ rst,                    // [N][256] fp32
    float* __restrict__ el, float* __restrict__ er)
{
    const int b = blockIdx.x;
    const int grp = b >> 5, w32 = b & 31;
    const int bx = grp * 8 + (w32 & 7);
    const int ny = w32 >> 3;
    if (bx >= (NNODES + 127) / 128) return;

    __shared__ __align__(16) char smem[32768];
    char* sA = smem;
    char* sB = smem + 16384;

    const int tid = threadIdx.x;
    const int w = tid >> 6, l = tid & 63;
    const int wm = w & 1, wn = w >> 1;
    const int row0 = bx * 128;

    f32x4 acc[4][4];
#pragma unroll
    for (int tm = 0; tm < 4; ++tm)
#pragma unroll
        for (int tn = 0; tn < 4; ++tn) acc[tm][tn] = (f32x4)0.f;

    const int srow = tid >> 3;
    const int sslot = tid & 7;

    for (int k0 = 0; k0 < 256; k0 += 64) {
        if (k0) __syncthreads();
#pragma unroll
        for (int it = 0; it < 4; ++it) {
            int r = srow + it * 32;
            int gr = row0 + r; if (gr >= NNODES) gr = NNODES - 1;
            int kc = sslot ^ (r & 7);
            const unsigned short* g = featb + (size_t)gr * 256 + k0 + kc * 8;
            void* sp = sA + (it * 256 + w * 64) * 16;
            __builtin_amdgcn_global_load_lds((glb_cvp)g, (lds_vp)sp, 16, 0, 0);
        }
#pragma unroll
        for (int it = 0; it < 4; ++it) {
            int r = srow + it * 32;
            int kc = sslot ^ (r & 7);
            const unsigned short* g = Wb + (size_t)(ny * 128 + r) * 256 + k0 + kc * 8;
            void* sp = sB + (it * 256 + w * 64) * 16;
            __builtin_amdgcn_global_load_lds((glb_cvp)g, (lds_vp)sp, 16, 0, 0);
        }
        __syncthreads();

        const int quad = l >> 4;
#pragma unroll
        for (int kk = 0; kk < 2; ++kk) {
            const int kc = kk * 4 + quad;
            bf16x8 af[4], bq[4];
#pragma unroll
            for (int tm = 0; tm < 4; ++tm) {
                int m = wm * 64 + tm * 16 + (l & 15);
                af[tm] = *(const bf16x8*)(sA + m * 128 + ((kc ^ (m & 7)) * 16));
            }
#pragma unroll
            for (int tn = 0; tn < 4; ++tn) {
                int n = wn * 64 + tn * 16 + (l & 15);
                bq[tn] = *(const bf16x8*)(sB + n * 128 + ((kc ^ (n & 7)) * 16));
            }
#pragma unroll
            for (int tm = 0; tm < 4; ++tm)
#pragma unroll
                for (int tn = 0; tn < 4; ++tn)
                    acc[tm][tn] = __builtin_amdgcn_mfma_f32_16x16x32_bf16(
                        af[tm], bq[tn], acc[tm][tn], 0, 0, 0);
        }
    }

    const int quad = l >> 4, c15 = l & 15;
    if (ny < 2) {
        // ---- fsb stores ----
#pragma unroll
        for (int tm = 0; tm < 4; ++tm) {
            int rb = row0 + wm * 64 + tm * 16 + quad * 4;
#pragma unroll
            for (int tn = 0; tn < 4; ++tn) {
                int cg = ny * 128 + wn * 64 + tn * 16 + c15;
#pragma unroll
                for (int reg = 0; reg < 4; ++reg) {
                    int r = rb + reg;
                    if (r < NNODES) fsb[(size_t)r * 256 + cg] = f2b(acc[tm][tn][reg]);
                }
            }
        }
        // ---- fused el/er: this wave owns head hh's full 64 columns ----
        const int hh = ny * 2 + wn;
        float alv[4], arv[4];
#pragma unroll
        for (int tn = 0; tn < 4; ++tn) {
            alv[tn] = attn_l[hh * 64 + tn * 16 + c15];
            arv[tn] = attn_r[hh * 64 + tn * 16 + c15];
        }
#pragma unroll
        for (int tm = 0; tm < 4; ++tm) {
#pragma unroll
            for (int reg = 0; reg < 4; ++reg) {
                float pl = 0.f, pr = 0.f;
#pragma unroll
                for (int tn = 0; tn < 4; ++tn) {
                    float v = acc[tm][tn][reg];
                    pl = fmaf(v, alv[tn], pl);
                    pr = fmaf(v, arv[tn], pr);
                }
#pragma unroll
                for (int d = 1; d < 16; d <<= 1) {
                    pl += __shfl_xor(pl, d);
                    pr += __shfl_xor(pr, d);
                }
                if (c15 == 0) {
                    int r = row0 + wm * 64 + tm * 16 + quad * 4 + reg;
                    if (r < NNODES) {
                        el[r * NHEAD + hh] = pl;
                        er[r * NHEAD + hh] = pr;
                    }
                }
            }
        }
    } else {
#pragma unroll
        for (int tm = 0; tm < 4; ++tm) {
            int rb = row0 + wm * 64 + tm * 16 + quad * 4;
#pragma unroll
            for (int tn = 0; tn < 4; ++tn) {
                int co = (ny - 2) * 128 + wn * 64 + tn * 16 + c15;
                float b2 = bias[co];
#pragma unroll
                for (int reg = 0; reg < 4; ++reg) {
                    int r = rb + reg;
                    if (r < NNODES) rst[(size_t)r * 256 + co] = acc[tm][tn][reg] + b2;
                }
            }
        }
    }
}

// ---------------- global max of el per head (for fixed softmax shift) ------
__global__ __launch_bounds__(256) void gmax_kernel(const float* __restrict__ el,
                                                   unsigned int* __restrict__ gmax)
{
    int t = blockIdx.x * 256 + threadIdx.x;
    float4 mx = make_float4(-1e30f, -1e30f, -1e30f, -1e30f);
    for (int n = t; n < NNODES; n += 64 * 256) {
        float4 v = *(const float4*)(el + (size_t)n * 4);
        mx.x = fmaxf(mx.x, v.x); mx.y = fmaxf(mx.y, v.y);
        mx.z = fmaxf(mx.z, v.z); mx.w = fmaxf(mx.w, v.w);
    }
#pragma unroll
    for (int d = 32; d > 0; d >>= 1) {
        mx.x = fmaxf(mx.x, __shfl_xor(mx.x, d));
        mx.y = fmaxf(mx.y, __shfl_xor(mx.y, d));
        mx.z = fmaxf(mx.z, __shfl_xor(mx.z, d));
        mx.w = fmaxf(mx.w, __shfl_xor(mx.w, d));
    }
    if ((threadIdx.x & 63) == 0) {
        atomicMax(&gmax[0], fmap(mx.x));
        atomicMax(&gmax[1], fmap(mx.y));
        atomicMax(&gmax[2], fmap(mx.z));
        atomicMax(&gmax[3], fmap(mx.w));
    }
}

// ---------------- CSR build (order-free grouping by dst) ----------------
__global__ __launch_bounds__(256) void count_kernel(const int* __restrict__ dst,
                                                    int* __restrict__ cnt)
{
    int e = blockIdx.x * 256 + threadIdx.x;
    if (e < NEDGES) atomicAdd(&cnt[dst[e]], 1);
}

// Wave-aggregated allocation: one atomic per wave instead of per thread.
__global__ __launch_bounds__(256) void offset_kernel(const int* __restrict__ cnt,
                                                     int* __restrict__ off,
                                                     int* __restrict__ cursor,
                                                     int* __restrict__ total)
{
    int n = blockIdx.x * 256 + threadIdx.x;
    int lane = threadIdx.x & 63;
    int c = (n < NNODES) ? cnt[n] : 0;
    int incl = c;
#pragma unroll
    for (int d = 1; d < 64; d <<= 1) {
        int t = __shfl_up(incl, d);
        if (lane >= d) incl += t;
    }
    int wsum = __shfl(incl, 63);
    int base = 0;
    if (lane == 0) base = atomicAdd(total, wsum);
    base = __shfl(base, 0);
    if (n < NNODES) {
        int o = base + incl - c;
        off[n] = o;
        cursor[n] = o;
    }
}

__global__ __launch_bounds__(256) void scatter_kernel(const int* __restrict__ dst,
                                                      int* __restrict__ cursor,
                                                      int* __restrict__ perm)
{
    int e = blockIdx.x * 256 + threadIdx.x;
    if (e < NEDGES) {
        int p = atomicAdd(&cursor[dst[e]], 1);
        perm[p] = e;
    }
}

// ---------------- agg: one wave per dst node ----------------
// Softmax shift is the node-independent-per-head bound M = lrelu(gmax_el + er):
// lrelu monotone => M >= every neighbor logit; softmax is shift-invariant, so
// the result is mathematically identical to the per-node max (no online pass).
// Sweep 2: two fsb rows per iteration (lanes 0-31 row j, lanes 32-63 row j+1),
// dwordx4 per lane -> 1 KB per load instruction, half the readlane/ds/load
// issue per edge, unroll 4 keeps 4 loads (4 KB) in flight.
__global__ __launch_bounds__(256) void agg_kernel(
    const int* __restrict__ src, const int* __restrict__ perm,
    const int* __restrict__ off, const int* __restrict__ cnt,
    const float* __restrict__ el, const float* __restrict__ er,
    const unsigned int* __restrict__ gmax,
    const unsigned short* __restrict__ fsb,
    float* __restrict__ rst,
    float* __restrict__ a_out)
{
    const int tid = threadIdx.x;
    const int wv = tid >> 6, lane = tid & 63;
    const int n = blockIdx.x * 4 + wv;
    const int deg = cnt[n];
    if (deg == 0) return;              // rst keeps residual
    const int o0 = off[n];

    __shared__ __align__(16) float a_sh[4][64][4];
    float* aw = &a_sh[wv][0][0];

    const float4 er4 = *(const float4*)(er + (size_t)n * NHEAD);
    const uint4 g4 = *(const uint4*)gmax;
    float4 M;
    M.x = lrelu(funmap(g4.x) + er4.x);
    M.y = lrelu(funmap(g4.y) + er4.y);
    M.z = lrelu(funmap(g4.z) + er4.z);
    M.w = lrelu(funmap(g4.w) + er4.w);

    // ---- sweep 1: s = sum exp(l - M) ----
    float4 s = make_float4(0.f, 0.f, 0.f, 0.f);
    int s0_save = 0, e0_save = 0;
    float4 l0_save = make_float4(0.f, 0.f, 0.f, 0.f);

    for (int base = 0; base < deg; base += 64) {
        int i = base + lane;
        bool valid = i < deg;
        int e = perm[o0 + (valid ? i : deg - 1)];
        int sidx = src[e];
        float4 ev = *(const float4*)(el + (size_t)sidx * NHEAD);
        float4 l;
        l.x = lrelu(ev.x + er4.x); l.y = lrelu(ev.y + er4.y);
        l.z = lrelu(ev.z + er4.z); l.w = lrelu(ev.w + er4.w);
        if (base == 0) { s0_save = sidx; e0_save = e; l0_save = l; }
        s.x += valid ? __expf(l.x - M.x) : 0.f;
        s.y += valid ? __expf(l.y - M.y) : 0.f;
        s.z += valid ? __expf(l.z - M.z) : 0.f;
        s.w += valid ? __expf(l.w - M.w) : 0.f;
    }
#pragma unroll
    for (int d = 32; d > 0; d >>= 1) {
        s.x += __shfl_xor(s.x, d);
        s.y += __shfl_xor(s.y, d);
        s.z += __shfl_xor(s.z, d);
        s.w += __shfl_xor(s.w, d);
    }
    float4 inv;
    inv.x = 1.f / fmaxf(s.x, 1e-20f);
    inv.y = 1.f / fmaxf(s.y, 1e-20f);
    inv.z = 1.f / fmaxf(s.z, 1e-20f);
    inv.w = 1.f / fmaxf(s.w, 1e-20f);

    // ---- sweep 2: normalized a + two-row dwordx4 gather-accumulate ----
    const int rsel = lane >> 5;          // 0: even rows, 1: odd rows
    const int c    = lane & 31;          // 32 lanes cover one 512B row
    const int h2   = c >> 3;             // head of this lane's 8 columns
    const unsigned int coff = (unsigned)c << 4;   // byte offset in row (16B)

    float acc[8];
#pragma unroll
    for (int k = 0; k < 8; ++k) acc[k] = 0.f;

    for (int base = 0; base < deg; base += 64) {
        int i = base + lane;
        bool valid = i < deg;
        int sidx, e; float4 l;
        if (base == 0) { sidx = s0_save; e = e0_save; l = l0_save; }
        else {
            e = perm[o0 + (valid ? i : deg - 1)];
            sidx = src[e];
            float4 ev = *(const float4*)(el + (size_t)sidx * NHEAD);
            l.x = lrelu(ev.x + er4.x); l.y = lrelu(ev.y + er4.y);
            l.z = lrelu(ev.z + er4.z); l.w = lrelu(ev.w + er4.w);
        }
        float4 a;
        a.x = valid ? __expf(l.x - M.x) * inv.x : 0.f;
        a.y = valid ? __expf(l.y - M.y) * inv.y : 0.f;
        a.z = valid ? __expf(l.z - M.z) * inv.z : 0.f;
        a.w = valid ? __expf(l.w - M.w) * inv.w : 0.f;
        *(float4*)(aw + (lane << 2)) = a;   // wave-synchronous staging (0-padded)

        if (valid) *(float4*)(a_out + (size_t)e * NHEAD) = a;   // fused a_out

        int nc = min(64, deg - base);
#pragma unroll 4
        for (int jj = 0; jj < nc; jj += 2) {
            int sjA = __builtin_amdgcn_readlane(sidx, jj);
            int sjB = __builtin_amdgcn_readlane(sidx, jj + 1);
            float av = aw[((jj + rsel) << 2) + h2];   // 0 for padded slots
            int sj = rsel ? sjB : sjA;
            unsigned int boff = ((unsigned)sj << 9) + coff;
            uint4 p = *(const uint4*)((const char*)fsb + boff);
            acc[0] = fmaf(av, __uint_as_float(p.x << 16),         acc[0]);
            acc[1] = fmaf(av, __uint_as_float(p.x & 0xffff0000u), acc[1]);
            acc[2] = fmaf(av, __uint_as_float(p.y << 16),         acc[2]);
            acc[3] = fmaf(av, __uint_as_float(p.y & 0xffff0000u), acc[3]);
            acc[4] = fmaf(av, __uint_as_float(p.z << 16),         acc[4]);
            acc[5] = fmaf(av, __uint_as_float(p.z & 0xffff0000u), acc[5]);
            acc[6] = fmaf(av, __uint_as_float(p.w << 16),         acc[6]);
            acc[7] = fmaf(av, __uint_as_float(p.w & 0xffff0000u), acc[7]);
        }
    }
    // combine even/odd halves: partner lane (xor 32) holds same columns
#pragma unroll
    for (int k = 0; k < 8; ++k) acc[k] += __shfl_xor(acc[k], 32);
    // each lane writes 16B: rsel=0 -> cols c*8..+3, rsel=1 -> cols c*8+4..+7
    float o0v = rsel ? acc[4] : acc[0];
    float o1v = rsel ? acc[5] : acc[1];
    float o2v = rsel ? acc[6] : acc[2];
    float o3v = rsel ? acc[7] : acc[3];
    size_t ro = (size_t)n * 256 + ((size_t)c << 3) + ((size_t)rsel << 2);
    float4 r = *(float4*)(rst + ro);
    r.x += o0v; r.y += o1v; r.z += o2v; r.w += o3v;
    *(float4*)(rst + ro) = r;
}

// ---------------- launch ----------------
extern "C" void kernel_launch(void* const* d_in, const int* in_sizes, int n_in,
                              void* d_out, int out_size, void* d_ws, size_t ws_size,
                              hipStream_t stream) {
    const float* feat   = (const float*)d_in[0];
    const int*   src    = (const int*)d_in[1];
    const int*   dst    = (const int*)d_in[2];
    const float* Wfc    = (const float*)d_in[3];
    const float* attn_l = (const float*)d_in[4];
    const float* attn_r = (const float*)d_in[5];
    const float* Wres   = (const float*)d_in[6];
    const float* bias   = (const float*)d_in[7];

    float* rst   = (float*)d_out;                              // N*256
    float* a_out = (float*)d_out + (size_t)NNODES * CDIM;      // E*4

    unsigned short* featb = (unsigned short*)d_ws;             // N*256 bf16
    unsigned short* fsb   = featb + (size_t)NNODES * CDIM;     // N*256 bf16
    unsigned short* Wb    = fsb + (size_t)NNODES * CDIM;       // 512*256 bf16
    float* el      = (float*)(Wb + 512 * 256);                 // N*4
    float* er      = el + (size_t)NNODES * NHEAD;              // N*4
    unsigned int* gmax = (unsigned int*)(er + (size_t)NNODES * NHEAD); // 4
    int* cnt    = (int*)(gmax + 4);                            // N
    int* off    = cnt + NNODES;                                // N
    int* cursor = off + NNODES;                                // N
    int* total  = cursor + NNODES;                             // 4
    int* perm   = total + 4;                                   // E

    hipMemsetAsync(cnt, 0, NNODES * sizeof(int), stream);
    hipMemsetAsync(total, 0, 4 * sizeof(int), stream);
    hipMemsetAsync(gmax, 0, 4 * sizeof(unsigned int), stream);

    cvt_feat<<<(NNODES * CDIM) / (256 * 4), 256, 0, stream>>>(feat, featb);
    cvt_w<<<(512 * 256) / (256 * 4), 256, 0, stream>>>(Wfc, Wres, Wb);

    // 782 row-blocks -> 98 groups of 8 -> grid 98*32 = 3136 (tail guarded)
    gemm_mfma<<<3136, 256, 0, stream>>>(featb, Wb, bias, attn_l, attn_r,
                                        fsb, rst, el, er);

    gmax_kernel<<<64, 256, 0, stream>>>(el, gmax);

    count_kernel<<<(NEDGES + 255) / 256, 256, 0, stream>>>(dst, cnt);
    offset_kernel<<<(NNODES + 255) / 256, 256, 0, stream>>>(cnt, off, cursor, total);
    scatter_kernel<<<(NEDGES + 255) / 256, 256, 0, stream>>>(dst, cursor, perm);

    agg_kernel<<<NNODES / 4, 256, 0, stream>>>(src, perm, off, cnt, el, er, gmax,
                                               fsb, rst, a_out);
}

// Round 5
// 654.129 us; speedup vs baseline: 1.0574x; 1.0574x over previous
//
#include <hip/hip_runtime.h>

// ---------------- problem constants ----------------
#define NNODES 100000
#define NEDGES 1600000
#define KDIM 256          // IN
#define CDIM 256          // H*F
#define NHEAD 4
#define FDIM 64
#define NEG 0.05f

typedef short bf16x8 __attribute__((ext_vector_type(8)));   // 8 bf16 in 4 VGPRs
typedef float f32x4  __attribute__((ext_vector_type(4)));
typedef __attribute__((address_space(3))) void*       lds_vp;
typedef __attribute__((address_space(1))) const void* glb_cvp;

__device__ __forceinline__ unsigned short f2b(float x) {   // fp32 -> bf16 RNE
    unsigned int u = __float_as_uint(x);
    return (unsigned short)((u + 0x7FFFu + ((u >> 16) & 1u)) >> 16);
}
__device__ __forceinline__ float b2f(unsigned short b) {
    return __uint_as_float(((unsigned int)b) << 16);
}
__device__ __forceinline__ float lrelu(float x) { return x > 0.f ? x : NEG * x; }

// monotone float<->uint mapping for atomicMax on signed floats
__device__ __forceinline__ unsigned int fmap(float f) {
    unsigned int u = __float_as_uint(f);
    return u ^ ((u >> 31) ? 0xFFFFFFFFu : 0x80000000u);
}
__device__ __forceinline__ float funmap(unsigned int u) {
    return __uint_as_float(u ^ ((u & 0x80000000u) ? 0x80000000u : 0xFFFFFFFFu));
}

// ---------------- fp32 -> bf16 converts ----------------
__global__ __launch_bounds__(256) void cvt_feat(const float* __restrict__ in,
                                                unsigned short* __restrict__ out)
{
    int i = (blockIdx.x * 256 + threadIdx.x) * 4;
    float4 v = *(const float4*)(in + i);
    ushort4 o;
    o.x = f2b(v.x); o.y = f2b(v.y); o.z = f2b(v.z); o.w = f2b(v.w);
    *(ushort4*)(out + i) = o;
}

__global__ __launch_bounds__(256) void cvt_w(const float* __restrict__ Wfc,
                                             const float* __restrict__ Wres,
                                             unsigned short* __restrict__ out)
{
    int i = (blockIdx.x * 256 + threadIdx.x) * 4;   // 131072 total
    float4 v = (i < 65536) ? *(const float4*)(Wfc + i)
                           : *(const float4*)(Wres + (i - 65536));
    ushort4 o;
    o.x = f2b(v.x); o.y = f2b(v.y); o.z = f2b(v.z); o.w = f2b(v.w);
    *(ushort4*)(out + i) = o;
}

// ---------------- bf16 MFMA dual GEMM + fused el/er epilogue ----------------
__global__ __launch_bounds__(256) void gemm_mfma(
    const unsigned short* __restrict__ featb,   // [N][256] bf16
    const unsigned short* __restrict__ Wb,      // [512][256] bf16
    const float* __restrict__ bias,
    const float* __restrict__ attn_l, const float* __restrict__ attn_r,
    unsigned short* __restrict__ fsb,           // [N][256] bf16
    float* __restrict__ rst,                    // [N][256] fp32
    float* __restrict__ el, float* __restrict__ er)
{
    const int b = blockIdx.x;
    const int grp = b >> 5, w32 = b & 31;
    const int bx = grp * 8 + (w32 & 7);
    const int ny = w32 >> 3;
    if (bx >= (NNODES + 127) / 128) return;

    __shared__ __align__(16) char smem[32768];
    char* sA = smem;
    char* sB = smem + 16384;

    const int tid = threadIdx.x;
    const int w = tid >> 6, l = tid & 63;
    const int wm = w & 1, wn = w >> 1;
    const int row0 = bx * 128;

    f32x4 acc[4][4];
#pragma unroll
    for (int tm = 0; tm < 4; ++tm)
#pragma unroll
        for (int tn = 0; tn < 4; ++tn) acc[tm][tn] = (f32x4)0.f;

    const int srow = tid >> 3;
    const int sslot = tid & 7;

    for (int k0 = 0; k0 < 256; k0 += 64) {
        if (k0) __syncthreads();
#pragma unroll
        for (int it = 0; it < 4; ++it) {
            int r = srow + it * 32;
            int gr = row0 + r; if (gr >= NNODES) gr = NNODES - 1;
            int kc = sslot ^ (r & 7);
            const unsigned short* g = featb + (size_t)gr * 256 + k0 + kc * 8;
            void* sp = sA + (it * 256 + w * 64) * 16;
            __builtin_amdgcn_global_load_lds((glb_cvp)g, (lds_vp)sp, 16, 0, 0);
        }
#pragma unroll
        for (int it = 0; it < 4; ++it) {
            int r = srow + it * 32;
            int kc = sslot ^ (r & 7);
            const unsigned short* g = Wb + (size_t)(ny * 128 + r) * 256 + k0 + kc * 8;
            void* sp = sB + (it * 256 + w * 64) * 16;
            __builtin_amdgcn_global_load_lds((glb_cvp)g, (lds_vp)sp, 16, 0, 0);
        }
        __syncthreads();

        const int quad = l >> 4;
#pragma unroll
        for (int kk = 0; kk < 2; ++kk) {
            const int kc = kk * 4 + quad;
            bf16x8 af[4], bq[4];
#pragma unroll
            for (int tm = 0; tm < 4; ++tm) {
                int m = wm * 64 + tm * 16 + (l & 15);
                af[tm] = *(const bf16x8*)(sA + m * 128 + ((kc ^ (m & 7)) * 16));
            }
#pragma unroll
            for (int tn = 0; tn < 4; ++tn) {
                int n = wn * 64 + tn * 16 + (l & 15);
                bq[tn] = *(const bf16x8*)(sB + n * 128 + ((kc ^ (n & 7)) * 16));
            }
#pragma unroll
            for (int tm = 0; tm < 4; ++tm)
#pragma unroll
                for (int tn = 0; tn < 4; ++tn)
                    acc[tm][tn] = __builtin_amdgcn_mfma_f32_16x16x32_bf16(
                        af[tm], bq[tn], acc[tm][tn], 0, 0, 0);
        }
    }

    const int quad = l >> 4, c15 = l & 15;
    if (ny < 2) {
        // ---- fsb stores ----
#pragma unroll
        for (int tm = 0; tm < 4; ++tm) {
            int rb = row0 + wm * 64 + tm * 16 + quad * 4;
#pragma unroll
            for (int tn = 0; tn < 4; ++tn) {
                int cg = ny * 128 + wn * 64 + tn * 16 + c15;
#pragma unroll
                for (int reg = 0; reg < 4; ++reg) {
                    int r = rb + reg;
                    if (r < NNODES) fsb[(size_t)r * 256 + cg] = f2b(acc[tm][tn][reg]);
                }
            }
        }
        // ---- fused el/er: this wave owns head hh's full 64 columns ----
        const int hh = ny * 2 + wn;
        float alv[4], arv[4];
#pragma unroll
        for (int tn = 0; tn < 4; ++tn) {
            alv[tn] = attn_l[hh * 64 + tn * 16 + c15];
            arv[tn] = attn_r[hh * 64 + tn * 16 + c15];
        }
#pragma unroll
        for (int tm = 0; tm < 4; ++tm) {
#pragma unroll
            for (int reg = 0; reg < 4; ++reg) {
                float pl = 0.f, pr = 0.f;
#pragma unroll
                for (int tn = 0; tn < 4; ++tn) {
                    float v = acc[tm][tn][reg];
                    pl = fmaf(v, alv[tn], pl);
                    pr = fmaf(v, arv[tn], pr);
                }
#pragma unroll
                for (int d = 1; d < 16; d <<= 1) {
                    pl += __shfl_xor(pl, d);
                    pr += __shfl_xor(pr, d);
                }
                if (c15 == 0) {
                    int r = row0 + wm * 64 + tm * 16 + quad * 4 + reg;
                    if (r < NNODES) {
                        el[r * NHEAD + hh] = pl;
                        er[r * NHEAD + hh] = pr;
                    }
                }
            }
        }
    } else {
#pragma unroll
        for (int tm = 0; tm < 4; ++tm) {
            int rb = row0 + wm * 64 + tm * 16 + quad * 4;
#pragma unroll
            for (int tn = 0; tn < 4; ++tn) {
                int co = (ny - 2) * 128 + wn * 64 + tn * 16 + c15;
                float b2 = bias[co];
#pragma unroll
                for (int reg = 0; reg < 4; ++reg) {
                    int r = rb + reg;
                    if (r < NNODES) rst[(size_t)r * 256 + co] = acc[tm][tn][reg] + b2;
                }
            }
        }
    }
}

// ---------------- global max of el per head (for fixed softmax shift) ------
__global__ __launch_bounds__(256) void gmax_kernel(const float* __restrict__ el,
                                                   unsigned int* __restrict__ gmax)
{
    int t = blockIdx.x * 256 + threadIdx.x;
    float4 mx = make_float4(-1e30f, -1e30f, -1e30f, -1e30f);
    for (int n = t; n < NNODES; n += 64 * 256) {
        float4 v = *(const float4*)(el + (size_t)n * 4);
        mx.x = fmaxf(mx.x, v.x); mx.y = fmaxf(mx.y, v.y);
        mx.z = fmaxf(mx.z, v.z); mx.w = fmaxf(mx.w, v.w);
    }
#pragma unroll
    for (int d = 32; d > 0; d >>= 1) {
        mx.x = fmaxf(mx.x, __shfl_xor(mx.x, d));
        mx.y = fmaxf(mx.y, __shfl_xor(mx.y, d));
        mx.z = fmaxf(mx.z, __shfl_xor(mx.z, d));
        mx.w = fmaxf(mx.w, __shfl_xor(mx.w, d));
    }
    if ((threadIdx.x & 63) == 0) {
        atomicMax(&gmax[0], fmap(mx.x));
        atomicMax(&gmax[1], fmap(mx.y));
        atomicMax(&gmax[2], fmap(mx.z));
        atomicMax(&gmax[3], fmap(mx.w));
    }
}

// ---------------- CSR build (order-free grouping by dst) ----------------
__global__ __launch_bounds__(256) void count_kernel(const int* __restrict__ dst,
                                                    int* __restrict__ cnt)
{
    int e = blockIdx.x * 256 + threadIdx.x;
    if (e < NEDGES) atomicAdd(&cnt[dst[e]], 1);
}

// Wave-aggregated allocation: one atomic per wave instead of per thread.
__global__ __launch_bounds__(256) void offset_kernel(const int* __restrict__ cnt,
                                                     int* __restrict__ off,
                                                     int* __restrict__ cursor,
                                                     int* __restrict__ total)
{
    int n = blockIdx.x * 256 + threadIdx.x;
    int lane = threadIdx.x & 63;
    int c = (n < NNODES) ? cnt[n] : 0;
    int incl = c;
#pragma unroll
    for (int d = 1; d < 64; d <<= 1) {
        int t = __shfl_up(incl, d);
        if (lane >= d) incl += t;
    }
    int wsum = __shfl(incl, 63);
    int base = 0;
    if (lane == 0) base = atomicAdd(total, wsum);
    base = __shfl(base, 0);
    if (n < NNODES) {
        int o = base + incl - c;
        off[n] = o;
        cursor[n] = o;
    }
}

// Also pre-gathers src into perm order: sperm[p] = src[e] (src[e] coalesced
// read here) so the agg sweeps never do a dependent random src gather.
// sperm ALIASES the featb region (dead after gemm_mfma, stream-ordered before
// this kernel) so the workspace footprint stays at the proven-to-fit size.
__global__ __launch_bounds__(256) void scatter_kernel(const int* __restrict__ dst,
                                                      const int* __restrict__ src,
                                                      int* __restrict__ cursor,
                                                      int* __restrict__ perm,
                                                      int* __restrict__ sperm)
{
    int e = blockIdx.x * 256 + threadIdx.x;
    if (e < NEDGES) {
        int s = src[e];
        int p = atomicAdd(&cursor[dst[e]], 1);
        perm[p] = e;
        sperm[p] = s;
    }
}

// ---------------- agg: one wave per dst node ----------------
// Softmax shift is the node-independent-per-head bound M = lrelu(gmax_el + er):
// lrelu monotone => M >= every neighbor logit; softmax shift-invariant => exact.
// Sweeps read sperm (src in perm order) COALESCED -> dependency chain is
// sperm load -> el gather (2 deep, was 3). Sweep 2 gathers two fsb rows per
// step, dwordx4 per lane, unroll 8 -> 8 KB per wave in flight (MLP doubled).
__global__ __launch_bounds__(256) void agg_kernel(
    const int* __restrict__ sperm, const int* __restrict__ perm,
    const int* __restrict__ off, const int* __restrict__ cnt,
    const float* __restrict__ el, const float* __restrict__ er,
    const unsigned int* __restrict__ gmax,
    const unsigned short* __restrict__ fsb,
    float* __restrict__ rst,
    float* __restrict__ a_out)
{
    const int tid = threadIdx.x;
    const int wv = tid >> 6, lane = tid & 63;
    const int n = blockIdx.x * 4 + wv;
    const int deg = cnt[n];
    if (deg == 0) return;              // rst keeps residual
    const int o0 = off[n];

    __shared__ __align__(16) float a_sh[4][64][4];
    float* aw = &a_sh[wv][0][0];

    const float4 er4 = *(const float4*)(er + (size_t)n * NHEAD);
    const uint4 g4 = *(const uint4*)gmax;
    float4 M;
    M.x = lrelu(funmap(g4.x) + er4.x);
    M.y = lrelu(funmap(g4.y) + er4.y);
    M.z = lrelu(funmap(g4.z) + er4.z);
    M.w = lrelu(funmap(g4.w) + er4.w);

    // ---- sweep 1: s = sum exp(l - M) ----
    float4 s = make_float4(0.f, 0.f, 0.f, 0.f);
    int s0_save = 0;
    float4 l0_save = make_float4(0.f, 0.f, 0.f, 0.f);

    for (int base = 0; base < deg; base += 64) {
        int i = base + lane;
        bool valid = i < deg;
        int sidx = sperm[o0 + (valid ? i : deg - 1)];
        float4 ev = *(const float4*)(el + (size_t)sidx * NHEAD);
        float4 l;
        l.x = lrelu(ev.x + er4.x); l.y = lrelu(ev.y + er4.y);
        l.z = lrelu(ev.z + er4.z); l.w = lrelu(ev.w + er4.w);
        if (base == 0) { s0_save = sidx; l0_save = l; }
        s.x += valid ? __expf(l.x - M.x) : 0.f;
        s.y += valid ? __expf(l.y - M.y) : 0.f;
        s.z += valid ? __expf(l.z - M.z) : 0.f;
        s.w += valid ? __expf(l.w - M.w) : 0.f;
    }
#pragma unroll
    for (int d = 32; d > 0; d >>= 1) {
        s.x += __shfl_xor(s.x, d);
        s.y += __shfl_xor(s.y, d);
        s.z += __shfl_xor(s.z, d);
        s.w += __shfl_xor(s.w, d);
    }
    float4 inv;
    inv.x = 1.f / fmaxf(s.x, 1e-20f);
    inv.y = 1.f / fmaxf(s.y, 1e-20f);
    inv.z = 1.f / fmaxf(s.z, 1e-20f);
    inv.w = 1.f / fmaxf(s.w, 1e-20f);

    // ---- sweep 2: normalized a + two-row dwordx4 gather-accumulate ----
    const int rsel = lane >> 5;          // 0: even rows, 1: odd rows
    const int c    = lane & 31;          // 32 lanes cover one 512B row
    const int h2   = c >> 3;             // head of this lane's 8 columns
    const unsigned int coff = (unsigned)c << 4;   // byte offset in row (16B)

    float acc[8];
#pragma unroll
    for (int k = 0; k < 8; ++k) acc[k] = 0.f;

    for (int base = 0; base < deg; base += 64) {
        int i = base + lane;
        bool valid = i < deg;
        int e = perm[o0 + (valid ? i : deg - 1)];   // coalesced (a_out index)
        int sidx; float4 l;
        if (base == 0) { sidx = s0_save; l = l0_save; }
        else {
            sidx = sperm[o0 + (valid ? i : deg - 1)];
            float4 ev = *(const float4*)(el + (size_t)sidx * NHEAD);
            l.x = lrelu(ev.x + er4.x); l.y = lrelu(ev.y + er4.y);
            l.z = lrelu(ev.z + er4.z); l.w = lrelu(ev.w + er4.w);
        }
        float4 a;
        a.x = valid ? __expf(l.x - M.x) * inv.x : 0.f;
        a.y = valid ? __expf(l.y - M.y) * inv.y : 0.f;
        a.z = valid ? __expf(l.z - M.z) * inv.z : 0.f;
        a.w = valid ? __expf(l.w - M.w) * inv.w : 0.f;
        *(float4*)(aw + (lane << 2)) = a;   // wave-synchronous staging (0-padded)

        if (valid) *(float4*)(a_out + (size_t)e * NHEAD) = a;   // fused a_out

        int nc = min(64, deg - base);
#pragma unroll 8
        for (int jj = 0; jj < nc; jj += 2) {
            int sjA = __builtin_amdgcn_readlane(sidx, jj);
            int sjB = __builtin_amdgcn_readlane(sidx, jj + 1);
            float av = aw[((jj + rsel) << 2) + h2];   // 0 for padded slots
            int sj = rsel ? sjB : sjA;
            unsigned int boff = ((unsigned)sj << 9) + coff;
            uint4 p = *(const uint4*)((const char*)fsb + boff);
            acc[0] = fmaf(av, __uint_as_float(p.x << 16),         acc[0]);
            acc[1] = fmaf(av, __uint_as_float(p.x & 0xffff0000u), acc[1]);
            acc[2] = fmaf(av, __uint_as_float(p.y << 16),         acc[2]);
            acc[3] = fmaf(av, __uint_as_float(p.y & 0xffff0000u), acc[3]);
            acc[4] = fmaf(av, __uint_as_float(p.z << 16),         acc[4]);
            acc[5] = fmaf(av, __uint_as_float(p.z & 0xffff0000u), acc[5]);
            acc[6] = fmaf(av, __uint_as_float(p.w << 16),         acc[6]);
            acc[7] = fmaf(av, __uint_as_float(p.w & 0xffff0000u), acc[7]);
        }
    }
    // combine even/odd halves: partner lane (xor 32) holds same columns
#pragma unroll
    for (int k = 0; k < 8; ++k) acc[k] += __shfl_xor(acc[k], 32);
    // each lane writes 16B: rsel=0 -> cols c*8..+3, rsel=1 -> cols c*8+4..+7
    float o0v = rsel ? acc[4] : acc[0];
    float o1v = rsel ? acc[5] : acc[1];
    float o2v = rsel ? acc[6] : acc[2];
    float o3v = rsel ? acc[7] : acc[3];
    size_t ro = (size_t)n * 256 + ((size_t)c << 3) + ((size_t)rsel << 2);
    float4 r = *(float4*)(rst + ro);
    r.x += o0v; r.y += o1v; r.z += o2v; r.w += o3v;
    *(float4*)(rst + ro) = r;
}

// ---------------- launch ----------------
extern "C" void kernel_launch(void* const* d_in, const int* in_sizes, int n_in,
                              void* d_out, int out_size, void* d_ws, size_t ws_size,
                              hipStream_t stream) {
    const float* feat   = (const float*)d_in[0];
    const int*   src    = (const int*)d_in[1];
    const int*   dst    = (const int*)d_in[2];
    const float* Wfc    = (const float*)d_in[3];
    const float* attn_l = (const float*)d_in[4];
    const float* attn_r = (const float*)d_in[5];
    const float* Wres   = (const float*)d_in[6];
    const float* bias   = (const float*)d_in[7];

    float* rst   = (float*)d_out;                              // N*256
    float* a_out = (float*)d_out + (size_t)NNODES * CDIM;      // E*4

    unsigned short* featb = (unsigned short*)d_ws;             // N*256 bf16
    unsigned short* fsb   = featb + (size_t)NNODES * CDIM;     // N*256 bf16
    unsigned short* Wb    = fsb + (size_t)NNODES * CDIM;       // 512*256 bf16
    float* el      = (float*)(Wb + 512 * 256);                 // N*4
    float* er      = el + (size_t)NNODES * NHEAD;              // N*4
    unsigned int* gmax = (unsigned int*)(er + (size_t)NNODES * NHEAD); // 4
    int* cnt    = (int*)(gmax + 4);                            // N
    int* off    = cnt + NNODES;                                // N
    int* cursor = off + NNODES;                                // N
    int* total  = cursor + NNODES;                             // 4
    int* perm   = total + 4;                                   // E
    // sperm reuses featb's storage (featb dead after gemm_mfma; scatter and
    // agg run strictly after it each call) -> no workspace growth.
    int* sperm  = (int*)featb;                                 // E (alias)

    hipMemsetAsync(cnt, 0, NNODES * sizeof(int), stream);
    hipMemsetAsync(total, 0, 4 * sizeof(int), stream);
    hipMemsetAsync(gmax, 0, 4 * sizeof(unsigned int), stream);

    cvt_feat<<<(NNODES * CDIM) / (256 * 4), 256, 0, stream>>>(feat, featb);
    cvt_w<<<(512 * 256) / (256 * 4), 256, 0, stream>>>(Wfc, Wres, Wb);

    // 782 row-blocks -> 98 groups of 8 -> grid 98*32 = 3136 (tail guarded)
    gemm_mfma<<<3136, 256, 0, stream>>>(featb, Wb, bias, attn_l, attn_r,
                                        fsb, rst, el, er);

    gmax_kernel<<<64, 256, 0, stream>>>(el, gmax);

    count_kernel<<<(NEDGES + 255) / 256, 256, 0, stream>>>(dst, cnt);
    offset_kernel<<<(NNODES + 255) / 256, 256, 0, stream>>>(cnt, off, cursor, total);
    scatter_kernel<<<(NEDGES + 255) / 256, 256, 0, stream>>>(dst, src, cursor,
                                                             perm, sperm);

    agg_kernel<<<NNODES / 4, 256, 0, stream>>>(sperm, perm, off, cnt, el, er, gmax,
                                               fsb, rst, a_out);
}

// Round 6
// 625.584 us; speedup vs baseline: 1.1056x; 1.0456x over previous
//
#include <hip/hip_runtime.h>

// ---------------- problem constants ----------------
#define NNODES 100000
#define NEDGES 1600000
#define KDIM 256          // IN
#define CDIM 256          // H*F
#define NHEAD 4
#define FDIM 64
#define NEG 0.05f

typedef short bf16x8 __attribute__((ext_vector_type(8)));   // 8 bf16 in 4 VGPRs
typedef float f32x4  __attribute__((ext_vector_type(4)));
typedef __attribute__((address_space(3))) void*       lds_vp;
typedef __attribute__((address_space(1))) const void* glb_cvp;

__device__ __forceinline__ unsigned short f2b(float x) {   // fp32 -> bf16 RNE
    unsigned int u = __float_as_uint(x);
    return (unsigned short)((u + 0x7FFFu + ((u >> 16) & 1u)) >> 16);
}
__device__ __forceinline__ float b2f(unsigned short b) {
    return __uint_as_float(((unsigned int)b) << 16);
}
__device__ __forceinline__ float lrelu(float x) { return x > 0.f ? x : NEG * x; }

// monotone float<->uint mapping for atomicMax on signed floats
__device__ __forceinline__ unsigned int fmap(float f) {
    unsigned int u = __float_as_uint(f);
    return u ^ ((u >> 31) ? 0xFFFFFFFFu : 0x80000000u);
}
__device__ __forceinline__ float funmap(unsigned int u) {
    return __uint_as_float(u ^ ((u & 0x80000000u) ? 0x80000000u : 0xFFFFFFFFu));
}

// ---------------- fp32 -> bf16 convert + fused edge count ----------------
// Blocks < 6250 also count one edge per thread (6250*256 == NEDGES): the
// random atomics hide under the convert's HBM streaming.
__global__ __launch_bounds__(256) void cvt_feat_count(
    const float* __restrict__ in, unsigned short* __restrict__ out,
    const int* __restrict__ dst, int* __restrict__ cnt)
{
    int i = (blockIdx.x * 256 + threadIdx.x) * 4;
    float4 v = *(const float4*)(in + i);
    ushort4 o;
    o.x = f2b(v.x); o.y = f2b(v.y); o.z = f2b(v.z); o.w = f2b(v.w);
    *(ushort4*)(out + i) = o;
    if (blockIdx.x < NEDGES / 256) {
        int e = blockIdx.x * 256 + threadIdx.x;
        atomicAdd(&cnt[dst[e]], 1);
    }
}

__global__ __launch_bounds__(256) void cvt_w(const float* __restrict__ Wfc,
                                             const float* __restrict__ Wres,
                                             unsigned short* __restrict__ out)
{
    int i = (blockIdx.x * 256 + threadIdx.x) * 4;   // 131072 total
    float4 v = (i < 65536) ? *(const float4*)(Wfc + i)
                           : *(const float4*)(Wres + (i - 65536));
    ushort4 o;
    o.x = f2b(v.x); o.y = f2b(v.y); o.z = f2b(v.z); o.w = f2b(v.w);
    *(ushort4*)(out + i) = o;
}

// ---------------- bf16 MFMA dual GEMM + fused el/er epilogue ----------------
__global__ __launch_bounds__(256) void gemm_mfma(
    const unsigned short* __restrict__ featb,   // [N][256] bf16
    const unsigned short* __restrict__ Wb,      // [512][256] bf16
    const float* __restrict__ bias,
    const float* __restrict__ attn_l, const float* __restrict__ attn_r,
    unsigned short* __restrict__ fsb,           // [N][256] bf16
    float* __restrict__ rst,                    // [N][256] fp32
    float* __restrict__ el, float* __restrict__ er)
{
    const int b = blockIdx.x;
    const int grp = b >> 5, w32 = b & 31;
    const int bx = grp * 8 + (w32 & 7);
    const int ny = w32 >> 3;
    if (bx >= (NNODES + 127) / 128) return;

    __shared__ __align__(16) char smem[32768];
    char* sA = smem;
    char* sB = smem + 16384;

    const int tid = threadIdx.x;
    const int w = tid >> 6, l = tid & 63;
    const int wm = w & 1, wn = w >> 1;
    const int row0 = bx * 128;

    f32x4 acc[4][4];
#pragma unroll
    for (int tm = 0; tm < 4; ++tm)
#pragma unroll
        for (int tn = 0; tn < 4; ++tn) acc[tm][tn] = (f32x4)0.f;

    const int srow = tid >> 3;
    const int sslot = tid & 7;

    for (int k0 = 0; k0 < 256; k0 += 64) {
        if (k0) __syncthreads();
#pragma unroll
        for (int it = 0; it < 4; ++it) {
            int r = srow + it * 32;
            int gr = row0 + r; if (gr >= NNODES) gr = NNODES - 1;
            int kc = sslot ^ (r & 7);
            const unsigned short* g = featb + (size_t)gr * 256 + k0 + kc * 8;
            void* sp = sA + (it * 256 + w * 64) * 16;
            __builtin_amdgcn_global_load_lds((glb_cvp)g, (lds_vp)sp, 16, 0, 0);
        }
#pragma unroll
        for (int it = 0; it < 4; ++it) {
            int r = srow + it * 32;
            int kc = sslot ^ (r & 7);
            const unsigned short* g = Wb + (size_t)(ny * 128 + r) * 256 + k0 + kc * 8;
            void* sp = sB + (it * 256 + w * 64) * 16;
            __builtin_amdgcn_global_load_lds((glb_cvp)g, (lds_vp)sp, 16, 0, 0);
        }
        __syncthreads();

        const int quad = l >> 4;
#pragma unroll
        for (int kk = 0; kk < 2; ++kk) {
            const int kc = kk * 4 + quad;
            bf16x8 af[4], bq[4];
#pragma unroll
            for (int tm = 0; tm < 4; ++tm) {
                int m = wm * 64 + tm * 16 + (l & 15);
                af[tm] = *(const bf16x8*)(sA + m * 128 + ((kc ^ (m & 7)) * 16));
            }
#pragma unroll
            for (int tn = 0; tn < 4; ++tn) {
                int n = wn * 64 + tn * 16 + (l & 15);
                bq[tn] = *(const bf16x8*)(sB + n * 128 + ((kc ^ (n & 7)) * 16));
            }
#pragma unroll
            for (int tm = 0; tm < 4; ++tm)
#pragma unroll
                for (int tn = 0; tn < 4; ++tn)
                    acc[tm][tn] = __builtin_amdgcn_mfma_f32_16x16x32_bf16(
                        af[tm], bq[tn], acc[tm][tn], 0, 0, 0);
        }
    }

    const int quad = l >> 4, c15 = l & 15;
    if (ny < 2) {
        // ---- fsb stores ----
#pragma unroll
        for (int tm = 0; tm < 4; ++tm) {
            int rb = row0 + wm * 64 + tm * 16 + quad * 4;
#pragma unroll
            for (int tn = 0; tn < 4; ++tn) {
                int cg = ny * 128 + wn * 64 + tn * 16 + c15;
#pragma unroll
                for (int reg = 0; reg < 4; ++reg) {
                    int r = rb + reg;
                    if (r < NNODES) fsb[(size_t)r * 256 + cg] = f2b(acc[tm][tn][reg]);
                }
            }
        }
        // ---- fused el/er: this wave owns head hh's full 64 columns ----
        const int hh = ny * 2 + wn;
        float alv[4], arv[4];
#pragma unroll
        for (int tn = 0; tn < 4; ++tn) {
            alv[tn] = attn_l[hh * 64 + tn * 16 + c15];
            arv[tn] = attn_r[hh * 64 + tn * 16 + c15];
        }
#pragma unroll
        for (int tm = 0; tm < 4; ++tm) {
#pragma unroll
            for (int reg = 0; reg < 4; ++reg) {
                float pl = 0.f, pr = 0.f;
#pragma unroll
                for (int tn = 0; tn < 4; ++tn) {
                    float v = acc[tm][tn][reg];
                    pl = fmaf(v, alv[tn], pl);
                    pr = fmaf(v, arv[tn], pr);
                }
#pragma unroll
                for (int d = 1; d < 16; d <<= 1) {
                    pl += __shfl_xor(pl, d);
                    pr += __shfl_xor(pr, d);
                }
                if (c15 == 0) {
                    int r = row0 + wm * 64 + tm * 16 + quad * 4 + reg;
                    if (r < NNODES) {
                        el[r * NHEAD + hh] = pl;
                        er[r * NHEAD + hh] = pr;
                    }
                }
            }
        }
    } else {
#pragma unroll
        for (int tm = 0; tm < 4; ++tm) {
            int rb = row0 + wm * 64 + tm * 16 + quad * 4;
#pragma unroll
            for (int tn = 0; tn < 4; ++tn) {
                int co = (ny - 2) * 128 + wn * 64 + tn * 16 + c15;
                float b2 = bias[co];
#pragma unroll
                for (int reg = 0; reg < 4; ++reg) {
                    int r = rb + reg;
                    if (r < NNODES) rst[(size_t)r * 256 + co] = acc[tm][tn][reg] + b2;
                }
            }
        }
    }
}

// ---------------- global max of el per head (for fixed softmax shift) ------
__global__ __launch_bounds__(256) void gmax_kernel(const float* __restrict__ el,
                                                   unsigned int* __restrict__ gmax)
{
    int t = blockIdx.x * 256 + threadIdx.x;
    float4 mx = make_float4(-1e30f, -1e30f, -1e30f, -1e30f);
    for (int n = t; n < NNODES; n += 64 * 256) {
        float4 v = *(const float4*)(el + (size_t)n * 4);
        mx.x = fmaxf(mx.x, v.x); mx.y = fmaxf(mx.y, v.y);
        mx.z = fmaxf(mx.z, v.z); mx.w = fmaxf(mx.w, v.w);
    }
#pragma unroll
    for (int d = 32; d > 0; d >>= 1) {
        mx.x = fmaxf(mx.x, __shfl_xor(mx.x, d));
        mx.y = fmaxf(mx.y, __shfl_xor(mx.y, d));
        mx.z = fmaxf(mx.z, __shfl_xor(mx.z, d));
        mx.w = fmaxf(mx.w, __shfl_xor(mx.w, d));
    }
    if ((threadIdx.x & 63) == 0) {
        atomicMax(&gmax[0], fmap(mx.x));
        atomicMax(&gmax[1], fmap(mx.y));
        atomicMax(&gmax[2], fmap(mx.z));
        atomicMax(&gmax[3], fmap(mx.w));
    }
}

// ---------------- CSR build (order-free grouping by dst) ----------------
// Wave-aggregated allocation: one atomic per wave instead of per thread.
__global__ __launch_bounds__(256) void offset_kernel(const int* __restrict__ cnt,
                                                     int* __restrict__ off,
                                                     int* __restrict__ cursor,
                                                     int* __restrict__ total)
{
    int n = blockIdx.x * 256 + threadIdx.x;
    int lane = threadIdx.x & 63;
    int c = (n < NNODES) ? cnt[n] : 0;
    int incl = c;
#pragma unroll
    for (int d = 1; d < 64; d <<= 1) {
        int t = __shfl_up(incl, d);
        if (lane >= d) incl += t;
    }
    int wsum = __shfl(incl, 63);
    int base = 0;
    if (lane == 0) base = atomicAdd(total, wsum);
    base = __shfl(base, 0);
    if (n < NNODES) {
        int o = base + incl - c;
        off[n] = o;
        cursor[n] = o;
    }
}

// One random 8B store per edge (edge id + src packed) instead of two 4B
// stores to two different cache lines -> halves scattered-line RMW traffic.
// eperm ALIASES the featb region (dead after gemm_mfma, stream-ordered).
__global__ __launch_bounds__(256) void scatter_kernel(const int* __restrict__ dst,
                                                      const int* __restrict__ src,
                                                      int* __restrict__ cursor,
                                                      int2* __restrict__ eperm)
{
    int e = blockIdx.x * 256 + threadIdx.x;
    if (e < NEDGES) {
        int s = src[e];
        int p = atomicAdd(&cursor[dst[e]], 1);
        eperm[p] = make_int2(e, s);
    }
}

// ---------------- agg: one wave per dst node ----------------
// Softmax shift is the node-independent-per-head bound M = lrelu(gmax_el + er):
// lrelu monotone => M >= every neighbor logit; softmax shift-invariant => exact.
// eperm (edge id, src) read coalesced; sweep 2 gathers two fsb rows per step,
// dwordx4 per lane, unroll 8.
__global__ __launch_bounds__(256) void agg_kernel(
    const int2* __restrict__ eperm,
    const int* __restrict__ off, const int* __restrict__ cnt,
    const float* __restrict__ el, const float* __restrict__ er,
    const unsigned int* __restrict__ gmax,
    const unsigned short* __restrict__ fsb,
    float* __restrict__ rst,
    float* __restrict__ a_out)
{
    const int tid = threadIdx.x;
    const int wv = tid >> 6, lane = tid & 63;
    const int n = blockIdx.x * 4 + wv;
    const int deg = cnt[n];
    if (deg == 0) return;              // rst keeps residual
    const int o0 = off[n];

    __shared__ __align__(16) float a_sh[4][64][4];
    float* aw = &a_sh[wv][0][0];

    const float4 er4 = *(const float4*)(er + (size_t)n * NHEAD);
    const uint4 g4 = *(const uint4*)gmax;
    float4 M;
    M.x = lrelu(funmap(g4.x) + er4.x);
    M.y = lrelu(funmap(g4.y) + er4.y);
    M.z = lrelu(funmap(g4.z) + er4.z);
    M.w = lrelu(funmap(g4.w) + er4.w);

    // ---- sweep 1: s = sum exp(l - M) ----
    float4 s = make_float4(0.f, 0.f, 0.f, 0.f);
    int s0_save = 0, e0_save = 0;
    float4 l0_save = make_float4(0.f, 0.f, 0.f, 0.f);

    for (int base = 0; base < deg; base += 64) {
        int i = base + lane;
        bool valid = i < deg;
        int2 es = eperm[o0 + (valid ? i : deg - 1)];
        int sidx = es.y;
        float4 ev = *(const float4*)(el + (size_t)sidx * NHEAD);
        float4 l;
        l.x = lrelu(ev.x + er4.x); l.y = lrelu(ev.y + er4.y);
        l.z = lrelu(ev.z + er4.z); l.w = lrelu(ev.w + er4.w);
        if (base == 0) { s0_save = sidx; e0_save = es.x; l0_save = l; }
        s.x += valid ? __expf(l.x - M.x) : 0.f;
        s.y += valid ? __expf(l.y - M.y) : 0.f;
        s.z += valid ? __expf(l.z - M.z) : 0.f;
        s.w += valid ? __expf(l.w - M.w) : 0.f;
    }
#pragma unroll
    for (int d = 32; d > 0; d >>= 1) {
        s.x += __shfl_xor(s.x, d);
        s.y += __shfl_xor(s.y, d);
        s.z += __shfl_xor(s.z, d);
        s.w += __shfl_xor(s.w, d);
    }
    float4 inv;
    inv.x = 1.f / fmaxf(s.x, 1e-20f);
    inv.y = 1.f / fmaxf(s.y, 1e-20f);
    inv.z = 1.f / fmaxf(s.z, 1e-20f);
    inv.w = 1.f / fmaxf(s.w, 1e-20f);

    // ---- sweep 2: normalized a + two-row dwordx4 gather-accumulate ----
    const int rsel = lane >> 5;          // 0: even rows, 1: odd rows
    const int c    = lane & 31;          // 32 lanes cover one 512B row
    const int h2   = c >> 3;             // head of this lane's 8 columns
    const unsigned int coff = (unsigned)c << 4;   // byte offset in row (16B)

    float acc[8];
#pragma unroll
    for (int k = 0; k < 8; ++k) acc[k] = 0.f;

    for (int base = 0; base < deg; base += 64) {
        int i = base + lane;
        bool valid = i < deg;
        int sidx, e; float4 l;
        if (base == 0) { sidx = s0_save; e = e0_save; l = l0_save; }
        else {
            int2 es = eperm[o0 + (valid ? i : deg - 1)];
            e = es.x; sidx = es.y;
            float4 ev = *(const float4*)(el + (size_t)sidx * NHEAD);
            l.x = lrelu(ev.x + er4.x); l.y = lrelu(ev.y + er4.y);
            l.z = lrelu(ev.z + er4.z); l.w = lrelu(ev.w + er4.w);
        }
        float4 a;
        a.x = valid ? __expf(l.x - M.x) * inv.x : 0.f;
        a.y = valid ? __expf(l.y - M.y) * inv.y : 0.f;
        a.z = valid ? __expf(l.z - M.z) * inv.z : 0.f;
        a.w = valid ? __expf(l.w - M.w) * inv.w : 0.f;
        *(float4*)(aw + (lane << 2)) = a;   // wave-synchronous staging (0-padded)

        if (valid) *(float4*)(a_out + (size_t)e * NHEAD) = a;   // fused a_out

        int nc = min(64, deg - base);
#pragma unroll 8
        for (int jj = 0; jj < nc; jj += 2) {
            int sjA = __builtin_amdgcn_readlane(sidx, jj);
            int sjB = __builtin_amdgcn_readlane(sidx, jj + 1);
            float av = aw[((jj + rsel) << 2) + h2];   // 0 for padded slots
            int sj = rsel ? sjB : sjA;
            unsigned int boff = ((unsigned)sj << 9) + coff;
            uint4 p = *(const uint4*)((const char*)fsb + boff);
            acc[0] = fmaf(av, __uint_as_float(p.x << 16),         acc[0]);
            acc[1] = fmaf(av, __uint_as_float(p.x & 0xffff0000u), acc[1]);
            acc[2] = fmaf(av, __uint_as_float(p.y << 16),         acc[2]);
            acc[3] = fmaf(av, __uint_as_float(p.y & 0xffff0000u), acc[3]);
            acc[4] = fmaf(av, __uint_as_float(p.z << 16),         acc[4]);
            acc[5] = fmaf(av, __uint_as_float(p.z & 0xffff0000u), acc[5]);
            acc[6] = fmaf(av, __uint_as_float(p.w << 16),         acc[6]);
            acc[7] = fmaf(av, __uint_as_float(p.w & 0xffff0000u), acc[7]);
        }
    }
    // combine even/odd halves: partner lane (xor 32) holds same columns
#pragma unroll
    for (int k = 0; k < 8; ++k) acc[k] += __shfl_xor(acc[k], 32);
    // each lane writes 16B: rsel=0 -> cols c*8..+3, rsel=1 -> cols c*8+4..+7
    float o0v = rsel ? acc[4] : acc[0];
    float o1v = rsel ? acc[5] : acc[1];
    float o2v = rsel ? acc[6] : acc[2];
    float o3v = rsel ? acc[7] : acc[3];
    size_t ro = (size_t)n * 256 + ((size_t)c << 3) + ((size_t)rsel << 2);
    float4 r = *(float4*)(rst + ro);
    r.x += o0v; r.y += o1v; r.z += o2v; r.w += o3v;
    *(float4*)(rst + ro) = r;
}

// ---------------- launch ----------------
extern "C" void kernel_launch(void* const* d_in, const int* in_sizes, int n_in,
                              void* d_out, int out_size, void* d_ws, size_t ws_size,
                              hipStream_t stream) {
    const float* feat   = (const float*)d_in[0];
    const int*   src    = (const int*)d_in[1];
    const int*   dst    = (const int*)d_in[2];
    const float* Wfc    = (const float*)d_in[3];
    const float* attn_l = (const float*)d_in[4];
    const float* attn_r = (const float*)d_in[5];
    const float* Wres   = (const float*)d_in[6];
    const float* bias   = (const float*)d_in[7];

    float* rst   = (float*)d_out;                              // N*256
    float* a_out = (float*)d_out + (size_t)NNODES * CDIM;      // E*4

    unsigned short* featb = (unsigned short*)d_ws;             // N*256 bf16
    unsigned short* fsb   = featb + (size_t)NNODES * CDIM;     // N*256 bf16
    unsigned short* Wb    = fsb + (size_t)NNODES * CDIM;       // 512*256 bf16
    float* el      = (float*)(Wb + 512 * 256);                 // N*4
    float* er      = el + (size_t)NNODES * NHEAD;              // N*4
    unsigned int* gmax = (unsigned int*)(er + (size_t)NNODES * NHEAD); // 4
    int* cnt    = (int*)(gmax + 4);                            // N
    int* off    = cnt + NNODES;                                // N
    int* cursor = off + NNODES;                                // N
    int* total  = cursor + NNODES;                             // 4
    // eperm reuses featb's storage (featb dead after gemm_mfma; scatter and
    // agg run strictly after it each call) -> no workspace growth.
    int2* eperm = (int2*)featb;                                // E int2 (alias)

    hipMemsetAsync(cnt, 0, NNODES * sizeof(int), stream);
    hipMemsetAsync(total, 0, 4 * sizeof(int), stream);
    hipMemsetAsync(gmax, 0, 4 * sizeof(unsigned int), stream);

    cvt_feat_count<<<(NNODES * CDIM) / (256 * 4), 256, 0, stream>>>(feat, featb,
                                                                    dst, cnt);
    cvt_w<<<(512 * 256) / (256 * 4), 256, 0, stream>>>(Wfc, Wres, Wb);

    // 782 row-blocks -> 98 groups of 8 -> grid 98*32 = 3136 (tail guarded)
    gemm_mfma<<<3136, 256, 0, stream>>>(featb, Wb, bias, attn_l, attn_r,
                                        fsb, rst, el, er);

    gmax_kernel<<<64, 256, 0, stream>>>(el, gmax);

    offset_kernel<<<(NNODES + 255) / 256, 256, 0, stream>>>(cnt, off, cursor, total);
    scatter_kernel<<<(NEDGES + 255) / 256, 256, 0, stream>>>(dst, src, cursor,
                                                             eperm);

    agg_kernel<<<NNODES / 4, 256, 0, stream>>>(eperm, off, cnt, el, er, gmax,
                                               fsb, rst, a_out);
}